// Round 1
// baseline (3389.290 us; speedup 1.0000x reference)
//
#include <hip/hip_runtime.h>
#include <math.h>

// Problem constants (fixed by setup_inputs)
// B=32 batch, N=2048 nodes, D=E=512, V=32000, T=32, 4D=2048 gates

__device__ inline float sigm(float x){ return 1.0f/(1.0f+expf(-x)); }

// ---------------- zero the output buffer (it is poisoned 0xAA each call) ----
__global__ void k_zero(float* __restrict__ p, int n4) {
  int i = blockIdx.x*blockDim.x + threadIdx.x;
  float4 z = {0.f,0.f,0.f,0.f};
  for (; i < n4; i += gridDim.x*blockDim.x) ((float4*)p)[i] = z;
}

// ---------------- h0 = mean of valid encoder states ------------------------
// grid (32 b, 16 chunks), 512 threads (d)
__global__ void k_init_partial(const float* __restrict__ enc,
                               const int* __restrict__ pad,
                               const int* __restrict__ ptr,
                               float* __restrict__ hpart,
                               float* __restrict__ cntp,
                               float* __restrict__ cntq) {
  int b = blockIdx.x, nc = blockIdx.y, d = threadIdx.x;
  int n0 = nc*128;
  float acc = 0.f; int cp = 0, cq = 0;
  for (int i = 0; i < 128; i++) {
    int n = n0 + i;
    int m = pad[b*2048 + n];
    cp += m; cq += ptr[b*2048 + n];
    if (m) acc += enc[((size_t)(b*2048 + n))*512 + d];
  }
  hpart[(b*16 + nc)*512 + d] = acc;
  if (d == 0) { cntp[b*16+nc] = (float)cp; cntq[b*16+nc] = (float)cq; }
}

// grid 32 (b), 512 threads: finalize h0/c0, thr=1/n_ptr, out[0,b,sos]=1
__global__ void k_init_final(const float* __restrict__ hpart,
                             const float* __restrict__ cntp,
                             const float* __restrict__ cntq,
                             float* __restrict__ h, float* __restrict__ c,
                             float* __restrict__ thr, float* __restrict__ out,
                             const int* __restrict__ sosp) {
  int b = blockIdx.x, d = threadIdx.x;
  float s = 0.f, cnt = 0.f;
  for (int nc = 0; nc < 16; nc++) { s += hpart[(b*16+nc)*512 + d]; cnt += cntp[b*16+nc]; }
  float v = s / cnt;
  h[b*512 + d] = v; c[b*512 + d] = v;
  if (d == 0) {
    float nq = 0.f;
    for (int nc = 0; nc < 16; nc++) nq += cntq[b*16+nc];
    thr[b] = 1.0f / nq;
    out[(size_t)b*32000 + sosp[0]] = 1.0f;
  }
}

// ---------------- gates = [x|h] @ [Wih|Whh]^T + biases ----------------------
// grid 64 blocks (32 j each), 256 threads. K=1024 processed as 4 passes of 256
// (2 x-passes gathered from emb, 2 h-passes). Wave handles 8 j's; lane = b +
// 32*khalf; LDS row stride 257 -> (b+k)%32 bank rotation, conflict-free.
__global__ __launch_bounds__(256) void k_gates(
    const float* __restrict__ emb, const float* __restrict__ h,
    const float* __restrict__ Wih, const float* __restrict__ Whh,
    const float* __restrict__ bih, const float* __restrict__ bhh,
    const int* __restrict__ target, const int* __restrict__ sosp,
    int s, float* __restrict__ gates) {
  __shared__ float lds[32*257];
  int tid = threadIdx.x;
  int w = tid >> 6, lane = tid & 63;
  int bl = lane & 31, kh = lane >> 5;
  int jb = blockIdx.x*32 + w*8;
  float acc[8];
#pragma unroll
  for (int jj = 0; jj < 8; jj++) acc[jj] = 0.f;

  for (int p = 0; p < 4; p++) {
    __syncthreads();
    for (int f = tid; f < 2048; f += 256) {          // 32 b x 64 float4
      int b = f >> 6, k = (f & 63) << 2;
      float4 v;
      if (p < 2) {
        int tok = (s == 0) ? sosp[0] : target[s*32 + b];
        v = *(const float4*)(emb + (size_t)tok*512 + p*256 + k);
      } else {
        v = *(const float4*)(h + b*512 + (p-2)*256 + k);
      }
      lds[b*257 + k]   = v.x; lds[b*257 + k+1] = v.y;
      lds[b*257 + k+2] = v.z; lds[b*257 + k+3] = v.w;
    }
    __syncthreads();
    const float* Wp = (p < 2) ? (Wih + p*256) : (Whh + (p-2)*256);
#pragma unroll 2
    for (int i = 0; i < 32; i++) {
      int k = kh*128 + i*4;
      float x0 = lds[bl*257+k], x1 = lds[bl*257+k+1];
      float x2 = lds[bl*257+k+2], x3 = lds[bl*257+k+3];
      const float* wr = Wp + jb*512 + k;
#pragma unroll
      for (int jj = 0; jj < 8; jj++) {
        float4 wv = *(const float4*)(wr + jj*512);
        acc[jj] += x0*wv.x + x1*wv.y + x2*wv.z + x3*wv.w;
      }
    }
  }
#pragma unroll
  for (int jj = 0; jj < 8; jj++) {
    float v = acc[jj] + __shfl_xor(acc[jj], 32, 64);
    if (kh == 0) gates[bl*2048 + jb + jj] = v + bih[jb+jj] + bhh[jb+jj];
  }
}

// ---------------- LSTM elementwise update ----------------------------------
__global__ void k_lstm(const float* __restrict__ gates,
                       float* __restrict__ h, float* __restrict__ c) {
  int idx = blockIdx.x*blockDim.x + threadIdx.x;
  if (idx >= 32*512) return;
  int b = idx >> 9, d = idx & 511;
  const float* g = gates + b*2048;
  float gi = g[d], gf = g[512+d], gg = g[1024+d], go = g[1536+d];
  float cn = sigm(gf)*c[idx] + sigm(gi)*tanhf(gg);
  float hn = sigm(go)*tanhf(cn);
  c[idx] = cn; h[idx] = hn;
}

// ---------------- q = h @ W_att^T ------------------------------------------
// grid 32 blocks (16 j each), 256 threads, wave handles 4 j's.
__global__ __launch_bounds__(256) void k_q(
    const float* __restrict__ h, const float* __restrict__ Watt,
    float* __restrict__ q) {
  __shared__ float lds[32*257];
  int tid = threadIdx.x;
  int w = tid >> 6, lane = tid & 63;
  int bl = lane & 31, kh = lane >> 5;
  int jb = blockIdx.x*16 + w*4;
  float acc[4] = {0.f,0.f,0.f,0.f};
  for (int p = 0; p < 2; p++) {
    __syncthreads();
    for (int f = tid; f < 2048; f += 256) {
      int b = f >> 6, k = (f & 63) << 2;
      float4 v = *(const float4*)(h + b*512 + p*256 + k);
      lds[b*257 + k]   = v.x; lds[b*257 + k+1] = v.y;
      lds[b*257 + k+2] = v.z; lds[b*257 + k+3] = v.w;
    }
    __syncthreads();
    const float* Wp = Watt + p*256;
#pragma unroll 4
    for (int i = 0; i < 32; i++) {
      int k = kh*128 + i*4;
      float x0 = lds[bl*257+k], x1 = lds[bl*257+k+1];
      float x2 = lds[bl*257+k+2], x3 = lds[bl*257+k+3];
      const float* wr = Wp + jb*512 + k;
#pragma unroll
      for (int jj = 0; jj < 4; jj++) {
        float4 wv = *(const float4*)(wr + jj*512);
        acc[jj] += x0*wv.x + x1*wv.y + x2*wv.z + x3*wv.w;
      }
    }
  }
#pragma unroll
  for (int jj = 0; jj < 4; jj++) {
    float v = acc[jj] + __shfl_xor(acc[jj], 32, 64);
    if (kh == 0) q[bl*512 + jb + jj] = v;
  }
}

// ---------------- scores[b,n] = enc[b,n,:] . q[b,:] (+ mask) ----------------
// grid (32 node-tiles, 32 b), 256 threads; one wave per node, lane covers 8
// contiguous floats via two float4 loads; q cached in registers per wave.
__global__ __launch_bounds__(256) void k_scores(
    const float* __restrict__ enc, const float* __restrict__ q,
    const int* __restrict__ pmask, float* __restrict__ sc) {
  int b = blockIdx.y;
  int w = threadIdx.x >> 6, lane = threadIdx.x & 63;
  float4 qa = *(const float4*)(q + b*512 + 4*lane);
  float4 qb = *(const float4*)(q + b*512 + 256 + 4*lane);
  int n0 = blockIdx.x*64 + w*16;
  for (int i = 0; i < 16; i++) {
    int n = n0 + i;
    const float* e = enc + ((size_t)(b*2048 + n))*512;
    float4 ea = *(const float4*)(e + 4*lane);
    float4 eb = *(const float4*)(e + 256 + 4*lane);
    float v = ea.x*qa.x + ea.y*qa.y + ea.z*qa.z + ea.w*qa.w
            + eb.x*qb.x + eb.y*qb.y + eb.z*qb.z + eb.w*qb.w;
#pragma unroll
    for (int off = 32; off; off >>= 1) v += __shfl_xor(v, off, 64);
    if (lane == 0)
      sc[b*2048 + n] = v + (pmask[b*2048 + n] ? 0.0f : -1e9f);
  }
}

// ---------------- softmax + threshold + scatter + eos -----------------------
// grid 32 (b), 256 threads. Output row pre-zeroed by k_zero.
__global__ __launch_bounds__(256) void k_scatter(
    const float* __restrict__ sc, const int* __restrict__ pmask,
    const int* __restrict__ tok, const float* __restrict__ thr,
    const int* __restrict__ eosp, float* __restrict__ outstep) {
  __shared__ float red[256];
  int b = blockIdx.x, tid = threadIdx.x;
  const float* s = sc + b*2048;
  float m = -3.4e38f;
  for (int n = tid; n < 2048; n += 256) m = fmaxf(m, s[n]);
  red[tid] = m; __syncthreads();
  for (int st = 128; st; st >>= 1) {
    if (tid < st) red[tid] = fmaxf(red[tid], red[tid+st]);
    __syncthreads();
  }
  float smax = red[0]; __syncthreads();
  float sum = 0.f;
  for (int n = tid; n < 2048; n += 256) sum += expf(s[n] - smax);
  red[tid] = sum; __syncthreads();
  for (int st = 128; st; st >>= 1) {
    if (tid < st) red[tid] += red[tid+st];
    __syncthreads();
  }
  float inv = 1.0f / red[0]; __syncthreads();
  float th = thr[b];
  float* orow = outstep + (size_t)b*32000;
  float keep = 0.f;
  for (int n = tid; n < 2048; n += 256) {
    float p = expf(s[n] - smax) * inv;
    if (pmask[b*2048 + n] && p >= th) {
      atomicAdd(orow + tok[b*2048 + n], p);
      keep += p;
    }
  }
  red[tid] = keep; __syncthreads();          // barrier also drains the atomics
  for (int st = 128; st; st >>= 1) {
    if (tid < st) red[tid] += red[tid+st];
    __syncthreads();
  }
  if (tid == 0) orow[eosp[0]] = 1.0f - red[0];
}

extern "C" void kernel_launch(void* const* d_in, const int* in_sizes, int n_in,
                              void* d_out, int out_size, void* d_ws, size_t ws_size,
                              hipStream_t stream) {
  const float* enc   = (const float*)d_in[0];
  const float* emb   = (const float*)d_in[1];
  const float* Wih   = (const float*)d_in[2];
  const float* Whh   = (const float*)d_in[3];
  const float* bih   = (const float*)d_in[4];
  const float* bhh   = (const float*)d_in[5];
  const float* Watt  = (const float*)d_in[6];
  const int*   pad   = (const int*)d_in[7];
  const int*   pmask = (const int*)d_in[8];
  const int*   tok   = (const int*)d_in[9];
  const int*   target= (const int*)d_in[10];
  const int*   sosp  = (const int*)d_in[11];
  const int*   eosp  = (const int*)d_in[12];
  float* out = (float*)d_out;

  // workspace layout (floats): ~1.8 MB total
  float* w      = (float*)d_ws;
  float* h      = w;                  // 32*512
  float* c      = h + 16384;          // 32*512
  float* q      = c + 16384;          // 32*512
  float* gates  = q + 16384;          // 32*2048
  float* scores = gates + 65536;      // 32*2048
  float* thr    = scores + 65536;     // 32
  float* hpart  = thr + 32;           // 32*16*512
  float* cntp   = hpart + 262144;     // 512
  float* cntq   = cntp + 512;         // 512

  k_zero<<<8192, 256, 0, stream>>>(out, 8192000);            // 32*32*32000/4
  k_init_partial<<<dim3(32,16), 512, 0, stream>>>(enc, pad, pmask, hpart, cntp, cntq);
  k_init_final<<<32, 512, 0, stream>>>(hpart, cntp, cntq, h, c, thr, out, sosp);

  for (int s = 0; s < 31; s++) {
    k_gates<<<64, 256, 0, stream>>>(emb, h, Wih, Whh, bih, bhh, target, sosp, s, gates);
    k_lstm<<<64, 256, 0, stream>>>(gates, h, c);
    k_q<<<32, 256, 0, stream>>>(h, Watt, q);
    k_scores<<<dim3(32,32), 256, 0, stream>>>(enc, q, pmask, scores);
    k_scatter<<<32, 256, 0, stream>>>(scores, pmask, tok, thr, eosp,
                                      out + (size_t)(s+1)*32*32000);
  }
}

// Round 2
// 1606.841 us; speedup vs baseline: 2.1093x; 2.1093x over previous
//
#include <hip/hip_runtime.h>
#include <math.h>

#define BB 32
#define NN 2048
#define DD 512
#define VV 32000
#define NSTEP 31

__device__ inline float sigm(float x){ return 1.0f/(1.0f+expf(-x)); }

// ---------------- zero the poisoned output ---------------------------------
__global__ void k_zero(float4* __restrict__ p, int n4) {
  int i = blockIdx.x*blockDim.x + threadIdx.x;
  float4 z = {0.f,0.f,0.f,0.f};
  for (; i < n4; i += gridDim.x*blockDim.x) p[i] = z;
}

// ---------------- counts, threshold, out[0] sos row ------------------------
__global__ __launch_bounds__(256) void k_cnt(
    const int* __restrict__ pad, const int* __restrict__ pmask,
    const int* __restrict__ sosp,
    float* __restrict__ cntp, float* __restrict__ thr, float* __restrict__ out) {
  __shared__ int r1[256], r2[256];
  int b = blockIdx.x, tid = threadIdx.x;
  int cp = 0, cq = 0;
  for (int n = tid; n < NN; n += 256) { cp += pad[b*NN+n]; cq += pmask[b*NN+n]; }
  r1[tid] = cp; r2[tid] = cq; __syncthreads();
  for (int st = 128; st; st >>= 1) {
    if (tid < st) { r1[tid] += r1[tid+st]; r2[tid] += r2[tid+st]; }
    __syncthreads();
  }
  if (tid == 0) {
    cntp[b] = (float)r1[0];
    thr[b]  = 1.0f/(float)r2[0];
    out[(size_t)b*VV + sosp[0]] = 1.0f;     // step-0 one-hot at sos
  }
}

// ---------------- h0 mean: partial sums ------------------------------------
// grid (32 b, 64 chunks), 128 threads (float4 over d). 32 rows per block.
__global__ __launch_bounds__(128) void k_meanpart(
    const float* __restrict__ enc, const int* __restrict__ pad,
    float* __restrict__ hpart) {
  int b = blockIdx.x, ch = blockIdx.y, kq = threadIdx.x;
  int n0 = ch*32;
  float4 acc = {0.f,0.f,0.f,0.f};
  for (int r = 0; r < 32; r++) {
    int n = n0 + r;
    if (pad[b*NN + n]) {
      float4 v = *(const float4*)(enc + ((size_t)(b*NN + n))*DD + kq*4);
      acc.x += v.x; acc.y += v.y; acc.z += v.z; acc.w += v.w;
    }
  }
  *(float4*)(hpart + ((size_t)(b*64 + ch))*DD + kq*4) = acc;
}

// grid 32 (b), 128 threads: finalize h0 = sum/cnt, c = h0
__global__ __launch_bounds__(128) void k_meanfin(
    const float* __restrict__ hpart, const float* __restrict__ cntp,
    float* __restrict__ h0, float* __restrict__ c) {
  int b = blockIdx.x, kq = threadIdx.x;
  float4 acc = {0.f,0.f,0.f,0.f};
  for (int ch = 0; ch < 64; ch++) {
    float4 v = *(const float4*)(hpart + ((size_t)(b*64 + ch))*DD + kq*4);
    acc.x += v.x; acc.y += v.y; acc.z += v.z; acc.w += v.w;
  }
  float ic = 1.0f/cntp[b];
  acc.x *= ic; acc.y *= ic; acc.z *= ic; acc.w *= ic;
  *(float4*)(h0 + b*DD + kq*4) = acc;
  *(float4*)(c  + b*DD + kq*4) = acc;
}

// ---------------- fused LSTM step: gates GEMM + pointwise ------------------
// grid 256 blocks; block bi owns d-cols {2bi, 2bi+1} -> 8 gate rows x 32 b.
// Thread (b = tid>>3, j = tid&7), j -> (gate g = j>>1, dd = j&1).
// [x|h] staged in two 64 KB LDS passes with XOR-chunk swizzle (bank-clean).
__global__ __launch_bounds__(256) void k_step(
    const float* __restrict__ emb, const float* __restrict__ hin,
    const float* __restrict__ Wih, const float* __restrict__ Whh,
    const float* __restrict__ bih, const float* __restrict__ bhh,
    const int* __restrict__ target, const int* __restrict__ sosp,
    int s, float* __restrict__ hout, float* __restrict__ c) {
  __shared__ float xs[BB*DD];                       // 64 KB
  int tid = threadIdx.x, bi = blockIdx.x;
  int j = tid & 7, b = tid >> 3;
  int d0 = bi*2;
  int row = (j >> 1)*DD + d0 + (j & 1);             // gate row in [0,2048)
  float acc = 0.f;
  for (int p = 0; p < 2; p++) {
    __syncthreads();
    for (int it = 0; it < 16; it++) {               // 4096 float4 slots
      int slot = tid + it*256;
      int sb = slot >> 7, kq = slot & 127;
      float4 v;
      if (p == 0) {
        int tok = (s == 0) ? sosp[0] : target[s*BB + sb];
        v = *(const float4*)(emb + (size_t)tok*DD + kq*4);
      } else {
        v = *(const float4*)(hin + sb*DD + kq*4);
      }
      *(float4*)(&xs[sb*DD + ((kq ^ (sb & 7)) << 2)]) = v;
    }
    __syncthreads();
    const float* wr = ((p == 0) ? Wih : Whh) + (size_t)row*DD;
    int bx = b & 7;
    for (int kq = 0; kq < 128; kq++) {
      float4 xv = *(const float4*)(&xs[b*DD + ((kq ^ bx) << 2)]);
      float4 wv = *(const float4*)(wr + kq*4);
      acc += xv.x*wv.x + xv.y*wv.y + xv.z*wv.z + xv.w*wv.w;
    }
  }
  acc += bih[row] + bhh[row];
  __syncthreads();
  xs[tid] = acc;                                    // gate exchange (reuse LDS)
  __syncthreads();
  if (tid < 64) {
    int bb = tid >> 1, dd = tid & 1;
    const float* g = &xs[bb*8];
    float gi = g[dd], gf = g[2+dd], gg = g[4+dd], go = g[6+dd];
    int dg = d0 + dd;
    float cv = c[bb*DD + dg];
    float cn = sigm(gf)*cv + sigm(gi)*tanhf(gg);
    float hn = sigm(go)*tanhf(cn);
    c[bb*DD + dg]    = cn;
    hout[bb*DD + dg] = hn;
  }
}

// ---------------- Q = H @ W_att^T for all steps ----------------------------
// grid (31 s, 16 jc), 256 threads; thread (b = tid>>3, j = tid&7) does 4 rows.
__global__ __launch_bounds__(256) void k_qall(
    const float* __restrict__ H, const float* __restrict__ Watt,
    float* __restrict__ Q) {
  __shared__ float hs[BB*DD];                       // 64 KB, XOR swizzle
  int s = blockIdx.x, jc = blockIdx.y, tid = threadIdx.x;
  const float* Hs = H + (size_t)s*BB*DD;
  for (int it = 0; it < 16; it++) {
    int slot = tid + it*256;
    int sb = slot >> 7, kq = slot & 127;
    float4 v = *(const float4*)(Hs + sb*DD + kq*4);
    *(float4*)(&hs[sb*DD + ((kq ^ (sb & 7)) << 2)]) = v;
  }
  __syncthreads();
  int j = tid & 7, b = tid >> 3, bx = b & 7;
  int r0 = jc*32 + j;
  float acc0 = 0.f, acc1 = 0.f, acc2 = 0.f, acc3 = 0.f;
  const float* w0 = Watt + (size_t)(r0     )*DD;
  const float* w1 = Watt + (size_t)(r0 +  8)*DD;
  const float* w2 = Watt + (size_t)(r0 + 16)*DD;
  const float* w3 = Watt + (size_t)(r0 + 24)*DD;
  for (int kq = 0; kq < 128; kq++) {
    float4 xv = *(const float4*)(&hs[b*DD + ((kq ^ bx) << 2)]);
    float4 wv;
    wv = *(const float4*)(w0 + kq*4); acc0 += xv.x*wv.x + xv.y*wv.y + xv.z*wv.z + xv.w*wv.w;
    wv = *(const float4*)(w1 + kq*4); acc1 += xv.x*wv.x + xv.y*wv.y + xv.z*wv.z + xv.w*wv.w;
    wv = *(const float4*)(w2 + kq*4); acc2 += xv.x*wv.x + xv.y*wv.y + xv.z*wv.z + xv.w*wv.w;
    wv = *(const float4*)(w3 + kq*4); acc3 += xv.x*wv.x + xv.y*wv.y + xv.z*wv.z + xv.w*wv.w;
  }
  float* Qs = Q + ((size_t)s*BB + b)*DD;
  Qs[r0] = acc0; Qs[r0+8] = acc1; Qs[r0+16] = acc2; Qs[r0+24] = acc3;
}

// ---------------- all scores: S[s][b][n] = enc[b,n,:] . Q[s,b,:] -----------
// grid (128 ntiles, 32 b), 256 threads. enc tile (16 rows) staged once in
// LDS (stride 520 -> bank-clean), reused across all 31 steps.
__global__ __launch_bounds__(256) void k_scores2(
    const float* __restrict__ enc, const float* __restrict__ Q,
    float* __restrict__ S) {
  __shared__ float es[16*520];                      // 33.3 KB
  __shared__ float qs[DD];                          // 2 KB
  int ntile = blockIdx.x, b = blockIdx.y, tid = threadIdx.x;
  int n0 = ntile*16;
  for (int it = 0; it < 8; it++) {                  // 2048 float4
    int slot = tid + it*256;
    int r = slot >> 7, kq = slot & 127;
    *(float4*)(&es[r*520 + kq*4]) =
        *(const float4*)(enc + ((size_t)(b*NN + n0 + r))*DD + kq*4);
  }
  int node = tid >> 4, dc = tid & 15;
  const float* er = &es[node*520];
  for (int s = 0; s < NSTEP; s++) {
    __syncthreads();                                // prev compute done / staging done
    if (tid < 128)
      *(float4*)(&qs[tid*4]) =
          *(const float4*)(Q + ((size_t)s*BB + b)*DD + tid*4);
    __syncthreads();
    float acc = 0.f;
#pragma unroll
    for (int i = 0; i < 8; i++) {
      int d = dc*4 + 64*i;
      float4 ev = *(const float4*)(er + d);
      float4 qv = *(const float4*)(&qs[d]);
      acc += ev.x*qv.x + ev.y*qv.y + ev.z*qv.z + ev.w*qv.w;
    }
    acc += __shfl_xor(acc, 8, 64);
    acc += __shfl_xor(acc, 4, 64);
    acc += __shfl_xor(acc, 2, 64);
    acc += __shfl_xor(acc, 1, 64);
    if (dc == 0) S[((size_t)s*BB + b)*NN + n0 + node] = acc;
  }
}

// ---------------- masked softmax + threshold + scatter + eos ---------------
// grid (31 s, 32 b), 256 threads. Mask applied here (== additive -1e9 mask).
__global__ __launch_bounds__(256) void k_scatter2(
    const float* __restrict__ S, const int* __restrict__ pmask,
    const int* __restrict__ tok, const float* __restrict__ thr,
    const int* __restrict__ eosp, float* __restrict__ out) {
  __shared__ float red[256];
  int s = blockIdx.x, b = blockIdx.y, tid = threadIdx.x;
  const float* sr = S + ((size_t)s*BB + b)*NN;
  const int* pm = pmask + b*NN;
  float m = -3.4e38f;
  for (int n = tid; n < NN; n += 256) if (pm[n]) m = fmaxf(m, sr[n]);
  red[tid] = m; __syncthreads();
  for (int st = 128; st; st >>= 1) {
    if (tid < st) red[tid] = fmaxf(red[tid], red[tid+st]);
    __syncthreads();
  }
  float smax = red[0]; __syncthreads();
  float sum = 0.f;
  for (int n = tid; n < NN; n += 256) if (pm[n]) sum += expf(sr[n] - smax);
  red[tid] = sum; __syncthreads();
  for (int st = 128; st; st >>= 1) {
    if (tid < st) red[tid] += red[tid+st];
    __syncthreads();
  }
  float inv = 1.0f/red[0]; __syncthreads();
  float th = thr[b];
  float* orow = out + ((size_t)(s+1)*BB + b)*VV;
  float keep = 0.f;
  for (int n = tid; n < NN; n += 256) {
    if (pm[n]) {
      float p = expf(sr[n] - smax)*inv;
      if (p >= th) { atomicAdd(orow + tok[b*NN + n], p); keep += p; }
    }
  }
  red[tid] = keep; __syncthreads();
  for (int st = 128; st; st >>= 1) {
    if (tid < st) red[tid] += red[tid+st];
    __syncthreads();
  }
  if (tid == 0) orow[eosp[0]] = 1.0f - red[0];
}

extern "C" void kernel_launch(void* const* d_in, const int* in_sizes, int n_in,
                              void* d_out, int out_size, void* d_ws, size_t ws_size,
                              hipStream_t stream) {
  const float* enc   = (const float*)d_in[0];
  const float* emb   = (const float*)d_in[1];
  const float* Wih   = (const float*)d_in[2];
  const float* Whh   = (const float*)d_in[3];
  const float* bih   = (const float*)d_in[4];
  const float* bhh   = (const float*)d_in[5];
  const float* Watt  = (const float*)d_in[6];
  const int*   pad   = (const int*)d_in[7];
  const int*   pmask = (const int*)d_in[8];
  const int*   tok   = (const int*)d_in[9];
  const int*   target= (const int*)d_in[10];
  const int*   sosp  = (const int*)d_in[11];
  const int*   eosp  = (const int*)d_in[12];
  float* out = (float*)d_out;

  // workspace layout (floats), ~16.5 MB total
  float* w     = (float*)d_ws;
  float* c     = w;                     // 32*512
  float* h0    = c     + BB*DD;         // 32*512
  float* H     = h0    + BB*DD;         // 31*32*512
  float* Q     = H     + NSTEP*BB*DD;   // 31*32*512
  float* S     = Q     + NSTEP*BB*DD;   // 31*32*2048
  float* hpart = S     + (size_t)NSTEP*BB*NN; // 32*64*512
  float* cntp  = hpart + 32*64*DD;      // 32
  float* thr   = cntp  + 32;            // 32

  k_zero<<<4096, 256, 0, stream>>>((float4*)out, 8192000);
  k_cnt<<<32, 256, 0, stream>>>(pad, pmask, sosp, cntp, thr, out);
  k_meanpart<<<dim3(32,64), 128, 0, stream>>>(enc, pad, hpart);
  k_meanfin<<<32, 128, 0, stream>>>(hpart, cntp, h0, c);

  for (int s = 0; s < NSTEP; s++) {
    const float* hin = (s == 0) ? h0 : (H + (size_t)(s-1)*BB*DD);
    k_step<<<256, 256, 0, stream>>>(emb, hin, Wih, Whh, bih, bhh,
                                    target, sosp, s, H + (size_t)s*BB*DD, c);
  }

  k_qall<<<dim3(NSTEP,16), 256, 0, stream>>>(H, Watt, Q);
  k_scores2<<<dim3(128,32), 256, 0, stream>>>(enc, Q, S);
  k_scatter2<<<dim3(NSTEP,32), 256, 0, stream>>>(S, pmask, tok, thr, eosp, out);
}

// Round 3
// 841.786 us; speedup vs baseline: 4.0263x; 1.9088x over previous
//
#include <hip/hip_runtime.h>
#include <math.h>

#define BB 32
#define NN 2048
#define DD 512
#define VV 32000
#define NSTEP 31

__device__ inline float sigm(float x){ return 1.0f/(1.0f+expf(-x)); }
__device__ inline float dot4(float4 a, float4 b){
  return a.x*b.x + a.y*b.y + a.z*b.z + a.w*b.w;
}

// Merged 8-way wave reduction: input a0..a7 are per-lane partials (each output
// needs a full 64-lane sum). Returns, in every lane, the full sum of a_{lane&7}.
// 34 inst for 8 outputs vs 96 for 8 separate butterflies.
__device__ inline float red8(float a0,float a1,float a2,float a3,
                             float a4,float a5,float a6,float a7,int lane){
  float m01 = ((lane&1)? a1:a0) + __shfl_xor(((lane&1)? a0:a1),1,64);
  float m23 = ((lane&1)? a3:a2) + __shfl_xor(((lane&1)? a2:a3),1,64);
  float m45 = ((lane&1)? a5:a4) + __shfl_xor(((lane&1)? a4:a5),1,64);
  float m67 = ((lane&1)? a7:a6) + __shfl_xor(((lane&1)? a6:a7),1,64);
  float m03 = ((lane&2)? m23:m01) + __shfl_xor(((lane&2)? m01:m23),2,64);
  float m47 = ((lane&2)? m67:m45) + __shfl_xor(((lane&2)? m45:m67),2,64);
  float m   = ((lane&4)? m47:m03) + __shfl_xor(((lane&4)? m03:m47),4,64);
  m += __shfl_xor(m,8,64); m += __shfl_xor(m,16,64); m += __shfl_xor(m,32,64);
  return m;
}

// ---------------- zero the poisoned output ---------------------------------
__global__ void k_zero(float4* __restrict__ p, int n4) {
  int i = blockIdx.x*blockDim.x + threadIdx.x;
  float4 z = {0.f,0.f,0.f,0.f};
  for (; i < n4; i += gridDim.x*blockDim.x) p[i] = z;
}

// ---------------- counts, threshold, out[0] sos row ------------------------
__global__ __launch_bounds__(256) void k_cnt(
    const int* __restrict__ pad, const int* __restrict__ pmask,
    const int* __restrict__ sosp,
    float* __restrict__ cntp, float* __restrict__ thr, float* __restrict__ out) {
  __shared__ int r1[256], r2[256];
  int b = blockIdx.x, tid = threadIdx.x;
  int cp = 0, cq = 0;
  for (int n = tid; n < NN; n += 256) { cp += pad[b*NN+n]; cq += pmask[b*NN+n]; }
  r1[tid] = cp; r2[tid] = cq; __syncthreads();
  for (int st = 128; st; st >>= 1) {
    if (tid < st) { r1[tid] += r1[tid+st]; r2[tid] += r2[tid+st]; }
    __syncthreads();
  }
  if (tid == 0) {
    cntp[b] = (float)r1[0];
    thr[b]  = 1.0f/(float)r2[0];
    out[(size_t)b*VV + sosp[0]] = 1.0f;
  }
}

// ---------------- h0 mean: partial sums (branch-free, pipelines) -----------
__global__ __launch_bounds__(128) void k_meanpart(
    const float* __restrict__ enc, const int* __restrict__ pad,
    float* __restrict__ hpart) {
  int b = blockIdx.x, ch = blockIdx.y, kq = threadIdx.x;
  int n0 = ch*32;
  float4 acc = {0.f,0.f,0.f,0.f};
#pragma unroll 8
  for (int r = 0; r < 32; r++) {
    int n = n0 + r;
    float msk = (float)pad[b*NN + n];
    float4 v = *(const float4*)(enc + ((size_t)(b*NN + n))*DD + kq*4);
    acc.x += msk*v.x; acc.y += msk*v.y; acc.z += msk*v.z; acc.w += msk*v.w;
  }
  *(float4*)(hpart + ((size_t)(b*64 + ch))*DD + kq*4) = acc;
}

__global__ __launch_bounds__(128) void k_meanfin(
    const float* __restrict__ hpart, const float* __restrict__ cntp,
    float* __restrict__ h0, float* __restrict__ c) {
  int b = blockIdx.x, kq = threadIdx.x;
  float4 acc = {0.f,0.f,0.f,0.f};
  for (int ch = 0; ch < 64; ch++) {
    float4 v = *(const float4*)(hpart + ((size_t)(b*64 + ch))*DD + kq*4);
    acc.x += v.x; acc.y += v.y; acc.z += v.z; acc.w += v.w;
  }
  float ic = 1.0f/cntp[b];
  acc.x *= ic; acc.y *= ic; acc.z *= ic; acc.w *= ic;
  *(float4*)(h0 + b*DD + kq*4) = acc;
  *(float4*)(c  + b*DD + kq*4) = acc;
}

// ---------------- G0[m,r] = emb[tok_m].Wih[r] + bih[r]+bhh[r], all steps ---
// grid (16 row-tiles of 128, 31 m-groups of 32). Wave holds 8 gathered x-rows
// in regs (16 float4), streams Wih rows coalesced; merged reduce; 8-lane store.
__global__ __launch_bounds__(256) void k_g0(
    const float* __restrict__ emb, const float* __restrict__ Wih,
    const float* __restrict__ bih, const float* __restrict__ bhh,
    const int* __restrict__ target, const int* __restrict__ sosp,
    float* __restrict__ G0) {
  int nt = blockIdx.x, mg = blockIdx.y;
  int w = threadIdx.x>>6, lane = threadIdx.x&63;
  int m0 = mg*32 + w*8;
  float4 x0[8], x1[8];
#pragma unroll
  for (int j = 0; j < 8; j++) {
    int m = m0 + j, s = m >> 5, bb = m & 31;
    int tok = (s == 0) ? sosp[0] : target[s*BB + bb];
    const float* xp = emb + (size_t)tok*DD + lane*4;
    x0[j] = *(const float4*)xp;
    x1[j] = *(const float4*)(xp + 256);
  }
  int r0 = nt*128;
#pragma unroll 2
  for (int i = 0; i < 128; i++) {
    int r = r0 + i;
    const float* wp = Wih + (size_t)r*DD + lane*4;
    float4 w0 = *(const float4*)wp, w1 = *(const float4*)(wp + 256);
    float a0 = dot4(w0,x0[0]) + dot4(w1,x1[0]);
    float a1 = dot4(w0,x0[1]) + dot4(w1,x1[1]);
    float a2 = dot4(w0,x0[2]) + dot4(w1,x1[2]);
    float a3 = dot4(w0,x0[3]) + dot4(w1,x1[3]);
    float a4 = dot4(w0,x0[4]) + dot4(w1,x1[4]);
    float a5 = dot4(w0,x0[5]) + dot4(w1,x1[5]);
    float a6 = dot4(w0,x0[6]) + dot4(w1,x1[6]);
    float a7 = dot4(w0,x0[7]) + dot4(w1,x1[7]);
    float v = red8(a0,a1,a2,a3,a4,a5,a6,a7,lane) + bih[r] + bhh[r];
    if (lane < 8) G0[(size_t)(m0 + lane)*2048 + r] = v;
  }
}

// ---------------- per-step: gates = G0[s] + h@Whh^T; LSTM pointwise --------
// grid 256 blocks; block bi owns d-cols {2bi,2bi+1} (8 gate rows) x 32 b.
// Whh rows live in registers (L1-resident across steps); h read from L2.
__global__ __launch_bounds__(256) void k_hstep(
    const float* __restrict__ hin, const float* __restrict__ Whh,
    const float* __restrict__ G0s, float* __restrict__ c,
    float* __restrict__ hout) {
  __shared__ float g[BB*8];
  int bi = blockIdx.x, d0 = bi*2;
  int w = threadIdx.x>>6, lane = threadIdx.x&63;
  float4 W0[8], W1[8];
#pragma unroll
  for (int j = 0; j < 8; j++) {
    int r = (j>>1)*DD + d0 + (j&1);
    const float* wp = Whh + (size_t)r*DD + lane*4;
    W0[j] = *(const float4*)wp; W1[j] = *(const float4*)(wp + 256);
  }
#pragma unroll
  for (int bb = 0; bb < 8; bb++) {
    int b = w*8 + bb;
    const float* hp = hin + b*DD + lane*4;
    float4 h0v = *(const float4*)hp, h1v = *(const float4*)(hp + 256);
    float a0 = dot4(h0v,W0[0]) + dot4(h1v,W1[0]);
    float a1 = dot4(h0v,W0[1]) + dot4(h1v,W1[1]);
    float a2 = dot4(h0v,W0[2]) + dot4(h1v,W1[2]);
    float a3 = dot4(h0v,W0[3]) + dot4(h1v,W1[3]);
    float a4 = dot4(h0v,W0[4]) + dot4(h1v,W1[4]);
    float a5 = dot4(h0v,W0[5]) + dot4(h1v,W1[5]);
    float a6 = dot4(h0v,W0[6]) + dot4(h1v,W1[6]);
    float a7 = dot4(h0v,W0[7]) + dot4(h1v,W1[7]);
    float v = red8(a0,a1,a2,a3,a4,a5,a6,a7,lane);
    if (lane < 8) g[b*8 + lane] = v;
  }
  __syncthreads();
  if (threadIdx.x < 64) {
    int b = threadIdx.x>>1, dd = threadIdx.x&1;
    const float* G = G0s + (size_t)b*2048 + d0 + dd;
    float gi = g[b*8 + 0 + dd] + G[0];
    float gf = g[b*8 + 2 + dd] + G[512];
    float gg = g[b*8 + 4 + dd] + G[1024];
    float go = g[b*8 + 6 + dd] + G[1536];
    int ci = b*DD + d0 + dd;
    float cn = sigm(gf)*c[ci] + sigm(gi)*tanhf(gg);
    float hn = sigm(go)*tanhf(cn);
    c[ci] = cn; hout[ci] = hn;
  }
}

// ---------------- Q[m,r] = H[m].Watt[r], all steps -------------------------
// grid (8 row-tiles of 64, 31 m-groups).
__global__ __launch_bounds__(256) void k_qallw(
    const float* __restrict__ H, const float* __restrict__ Watt,
    float* __restrict__ Q) {
  int nt = blockIdx.x, mg = blockIdx.y;
  int w = threadIdx.x>>6, lane = threadIdx.x&63;
  int m0 = mg*32 + w*8;
  float4 x0[8], x1[8];
#pragma unroll
  for (int j = 0; j < 8; j++) {
    const float* xp = H + (size_t)(m0 + j)*DD + lane*4;
    x0[j] = *(const float4*)xp; x1[j] = *(const float4*)(xp + 256);
  }
  int r0 = nt*64;
#pragma unroll 2
  for (int i = 0; i < 64; i++) {
    int r = r0 + i;
    const float* wp = Watt + (size_t)r*DD + lane*4;
    float4 w0 = *(const float4*)wp, w1 = *(const float4*)(wp + 256);
    float a0 = dot4(w0,x0[0]) + dot4(w1,x1[0]);
    float a1 = dot4(w0,x0[1]) + dot4(w1,x1[1]);
    float a2 = dot4(w0,x0[2]) + dot4(w1,x1[2]);
    float a3 = dot4(w0,x0[3]) + dot4(w1,x1[3]);
    float a4 = dot4(w0,x0[4]) + dot4(w1,x1[4]);
    float a5 = dot4(w0,x0[5]) + dot4(w1,x1[5]);
    float a6 = dot4(w0,x0[6]) + dot4(w1,x1[6]);
    float a7 = dot4(w0,x0[7]) + dot4(w1,x1[7]);
    float v = red8(a0,a1,a2,a3,a4,a5,a6,a7,lane);
    if (lane < 8) Q[(size_t)(m0 + lane)*DD + r] = v;
  }
}

// ---------------- S[s,b,n] = enc[b,n,:].Q[s*32+b,:] ------------------------
// grid (16 node-tiles of 128, 32 b). Wave w holds Q for steps w*8..w*8+7 in
// registers; streams enc rows coalesced global->reg (no LDS at all).
__global__ __launch_bounds__(256) void k_scores3(
    const float* __restrict__ enc, const float* __restrict__ Q,
    float* __restrict__ S) {
  int nt = blockIdx.x, b = blockIdx.y;
  int w = threadIdx.x>>6, lane = threadIdx.x&63;
  int s0 = w*8;
  float4 q0[8], q1[8];
#pragma unroll
  for (int j = 0; j < 8; j++) {
    const float* qp = Q + (size_t)((s0 + j)*BB + b)*DD + lane*4;  // Q padded to 32 slices
    q0[j] = *(const float4*)qp; q1[j] = *(const float4*)(qp + 256);
  }
  int n0 = nt*128;
  int sl = s0 + (lane & 7);
#pragma unroll 2
  for (int i = 0; i < 128; i++) {
    int n = n0 + i;
    const float* ep = enc + ((size_t)(b*NN + n))*DD + lane*4;
    float4 e0 = *(const float4*)ep, e1 = *(const float4*)(ep + 256);
    float a0 = dot4(e0,q0[0]) + dot4(e1,q1[0]);
    float a1 = dot4(e0,q0[1]) + dot4(e1,q1[1]);
    float a2 = dot4(e0,q0[2]) + dot4(e1,q1[2]);
    float a3 = dot4(e0,q0[3]) + dot4(e1,q1[3]);
    float a4 = dot4(e0,q0[4]) + dot4(e1,q1[4]);
    float a5 = dot4(e0,q0[5]) + dot4(e1,q1[5]);
    float a6 = dot4(e0,q0[6]) + dot4(e1,q1[6]);
    float a7 = dot4(e0,q0[7]) + dot4(e1,q1[7]);
    float v = red8(a0,a1,a2,a3,a4,a5,a6,a7,lane);
    if (lane < 8 && sl < NSTEP) S[((size_t)sl*BB + b)*NN + n] = v;
  }
}

// ---------------- masked softmax + threshold + scatter + eos ---------------
__global__ __launch_bounds__(256) void k_scatter2(
    const float* __restrict__ S, const int* __restrict__ pmask,
    const int* __restrict__ tok, const float* __restrict__ thr,
    const int* __restrict__ eosp, float* __restrict__ out) {
  __shared__ float red[256];
  __shared__ float ex[NN];
  int s = blockIdx.x, b = blockIdx.y, tid = threadIdx.x;
  const float* sr = S + ((size_t)s*BB + b)*NN;
  const int* pm = pmask + b*NN;
  float m = -3.4e38f;
  for (int n = tid; n < NN; n += 256) if (pm[n]) m = fmaxf(m, sr[n]);
  red[tid] = m; __syncthreads();
  for (int st = 128; st; st >>= 1) {
    if (tid < st) red[tid] = fmaxf(red[tid], red[tid+st]);
    __syncthreads();
  }
  float smax = red[0]; __syncthreads();
  float sum = 0.f;
  for (int n = tid; n < NN; n += 256) {
    float e = pm[n] ? expf(sr[n] - smax) : 0.f;
    ex[n] = e; sum += e;
  }
  red[tid] = sum; __syncthreads();
  for (int st = 128; st; st >>= 1) {
    if (tid < st) red[tid] += red[tid+st];
    __syncthreads();
  }
  float inv = 1.0f/red[0];
  float th = thr[b];
  float* orow = out + ((size_t)(s+1)*BB + b)*VV;
  float keep = 0.f;
  for (int n = tid; n < NN; n += 256) {
    float p = ex[n]*inv;                 // masked nodes have p=0 < th
    if (p >= th) { atomicAdd(orow + tok[b*NN + n], p); keep += p; }
  }
  __syncthreads();
  red[tid] = keep; __syncthreads();
  for (int st = 128; st; st >>= 1) {
    if (tid < st) red[tid] += red[tid+st];
    __syncthreads();
  }
  if (tid == 0) orow[eosp[0]] = 1.0f - red[0];
}

extern "C" void kernel_launch(void* const* d_in, const int* in_sizes, int n_in,
                              void* d_out, int out_size, void* d_ws, size_t ws_size,
                              hipStream_t stream) {
  const float* enc   = (const float*)d_in[0];
  const float* emb   = (const float*)d_in[1];
  const float* Wih   = (const float*)d_in[2];
  const float* Whh   = (const float*)d_in[3];
  const float* bih   = (const float*)d_in[4];
  const float* bhh   = (const float*)d_in[5];
  const float* Watt  = (const float*)d_in[6];
  const int*   pad   = (const int*)d_in[7];
  const int*   pmask = (const int*)d_in[8];
  const int*   tok   = (const int*)d_in[9];
  const int*   target= (const int*)d_in[10];
  const int*   sosp  = (const int*)d_in[11];
  const int*   eosp  = (const int*)d_in[12];
  float* out = (float*)d_out;

  // workspace layout (floats), ~20.5 MB. hpart aliases G0 (used only before it).
  float* w    = (float*)d_ws;
  float* c    = w;                          // 32*512
  float* h0   = c    + BB*DD;               // 32*512
  float* H    = h0   + BB*DD;               // 31*32*512
  float* Q    = H    + NSTEP*BB*DD;         // padded: 32*32*512
  float* S    = Q    + 32*BB*DD;            // 31*32*2048
  float* G0   = S    + (size_t)NSTEP*BB*NN; // 992*2048
  float* cntp = G0   + (size_t)992*2048;    // 32
  float* thr  = cntp + 32;                  // 32
  float* hpart = G0;                        // 32*64*512 (alias, pre-G0 only)

  k_zero<<<4096, 256, 0, stream>>>((float4*)out, 8192000);
  k_cnt<<<32, 256, 0, stream>>>(pad, pmask, sosp, cntp, thr, out);
  k_meanpart<<<dim3(32,64), 128, 0, stream>>>(enc, pad, hpart);
  k_meanfin<<<32, 128, 0, stream>>>(hpart, cntp, h0, c);

  k_g0<<<dim3(16,31), 256, 0, stream>>>(emb, Wih, bih, bhh, target, sosp, G0);

  for (int s = 0; s < NSTEP; s++) {
    const float* hin = (s == 0) ? h0 : (H + (size_t)(s-1)*BB*DD);
    k_hstep<<<256, 256, 0, stream>>>(hin, Whh, G0 + (size_t)s*BB*2048, c,
                                     H + (size_t)s*BB*DD);
  }

  k_qallw<<<dim3(8,31), 256, 0, stream>>>(H, Watt, Q);
  k_scores3<<<dim3(16,32), 256, 0, stream>>>(enc, Q, S);
  k_scatter2<<<dim3(NSTEP,32), 256, 0, stream>>>(S, pmask, tok, thr, eosp, out);
}